// Round 1
// baseline (688.294 us; speedup 1.0000x reference)
//
#include <hip/hip_runtime.h>

#define DD 32
#define HH 128
#define WW 128
#define CCH 96
#define NROW (DD*HH)          // 4096
#define NVOX (NROW*WW)        // 524288
#define NTOK 8192
#define NCLU 64

// ---- workspace layout (float offsets) ----
#define Z1_OFF    0ll
#define F_OFF     (9ll*NVOX)                  // 4718592
#define NCP_OFF   (F_OFF + NVOX)              // 5242880  (128 x 4096)
#define ZP_OFF    (NCP_OFF + 128ll*4096)      // 5767168  (128 x 64)
#define SSUM_OFF  (ZP_OFF + 8192)             // 5775360  (64)
#define SINV_OFF  (SSUM_OFF + 64)             // 5775424  (64)
#define CS_OFF    (SINV_OFF + 64)             // 5775488  (4096)
#define QWT_OFF   (CS_OFF + 4096)             // 5779584  (4096)
#define W2T_OFF   (QWT_OFF + 4096)            // 5783680  (2592)
#define NCC_OFF   (W2T_OFF + 2592)            // 5786272  (4096)
#define KT_OFF    (NCC_OFF + 4096)            // 5790368  (4096)
#define VV_OFF    (KT_OFF + 4096)             // 5794464  (4096)
#define O1_OFF    (VV_OFF + 4096)             // 5798560  (524288)
#define WS_FLOATS (O1_OFF + NVOX)             // 6322848

// ============================================================
// K1: fold w-axis taps: z'[j=kd*3+kh][voxel] = sum_c sum_kw x[d,h,w+kw-1,c]*W[c,kd,kh,kw]
// one block per (d,h) row; LDS-staged x row in 48-channel chunks.
// ============================================================
__global__ __launch_bounds__(128) void k1_zplanes(
    const float* __restrict__ x, const float* __restrict__ wg,
    float* __restrict__ z1)
{
  const int r = blockIdx.x;          // d*128 + h
  const int t = threadIdx.x;         // w
  __shared__ float xs[130][53];      // [w+1][c-chunk], stride 53 (odd -> conflict-free)
  float acc[9];
  #pragma unroll
  for (int j = 0; j < 9; ++j) acc[j] = 0.f;
  const long rowbase = (long)r * WW * CCH;

  for (int c0 = 0; c0 < CCH; c0 += 48) {
    for (int i4 = t; i4 < 130*12; i4 += 128) {
      int wp = i4 / 12, cq = (i4 % 12) * 4;
      float4 v = make_float4(0.f, 0.f, 0.f, 0.f);
      if (wp >= 1 && wp <= 128)
        v = *(const float4*)&x[rowbase + (long)(wp-1)*CCH + c0 + cq];
      xs[wp][cq+0] = v.x; xs[wp][cq+1] = v.y; xs[wp][cq+2] = v.z; xs[wp][cq+3] = v.w;
    }
    __syncthreads();
    #pragma unroll 4
    for (int cc = 0; cc < 48; ++cc) {
      const int c = c0 + cc;
      const float xm = xs[t][cc], x0v = xs[t+1][cc], xp = xs[t+2][cc];
      const float* wrow = &wg[c*27];           // uniform index -> scalar loads
      #pragma unroll
      for (int j = 0; j < 9; ++j)
        acc[j] += xm*wrow[j*3+0] + x0v*wrow[j*3+1] + xp*wrow[j*3+2];
    }
    __syncthreads();
  }
  #pragma unroll
  for (int j = 0; j < 9; ++j)
    z1[(long)j*NVOX + (long)r*WW + t] = acc[j];
}

// ============================================================
// K2: gather 9 shifted planes -> dnx, write token-layout F, accumulate per-f sumsq
// ============================================================
__global__ __launch_bounds__(128) void k2_combine(
    const float* __restrict__ z1, const float* __restrict__ dwc_b,
    float* __restrict__ Fb, float* __restrict__ ssum)
{
  const int r = blockIdx.x;
  const int t = threadIdx.x;
  const int d = r >> 7, h = r & 127;
  float y = dwc_b[0];
  #pragma unroll
  for (int kd = 0; kd < 3; ++kd) {
    const int dd = d + kd - 1;
    if (dd < 0 || dd >= DD) continue;
    #pragma unroll
    for (int kh = 0; kh < 3; ++kh) {
      const int h2 = h + kh - 1;
      if (h2 < 0 || h2 >= HH) continue;
      y += z1[(long)(kd*3+kh)*NVOX + (long)(dd*HH + h2)*WW + t];
    }
  }
  const int n = (d>>2)*1024 + (h>>2)*32 + (t>>2);
  const int f = (d&3)*16 + (h&3)*4 + (t&3);
  Fb[n*64 + f] = y;
  float s = y*y;
  s += __shfl_xor(s, 4);  s += __shfl_xor(s, 8);
  s += __shfl_xor(s, 16); s += __shfl_xor(s, 32);
  if ((t & 63) < 4) atomicAdd(&ssum[(d&3)*16 + (h&3)*4 + (t&3)], s);
}

// ============================================================
// K3: Sinv = 1/max(sqrt(ssum),eps); fold into centroids (Cs) and q_w (QWT, transposed);
//     build transposed upc weights W2T[tap][oc].
// ============================================================
__global__ __launch_bounds__(256) void k3_prep(
    const float* __restrict__ ssum, const float* __restrict__ centroids,
    const float* __restrict__ q_w, const float* __restrict__ upc_w,
    float* __restrict__ sinv, float* __restrict__ cs,
    float* __restrict__ qwt, float* __restrict__ w2t)
{
  __shared__ float sl[64];
  const int t = threadIdx.x;
  if (t < 64) {
    float v = 1.f / fmaxf(sqrtf(ssum[t]), 1e-12f);
    sinv[t] = v; sl[t] = v;
  }
  __syncthreads();
  for (int i = t; i < 4096; i += 256) cs[i] = centroids[i] * sl[i & 63];
  for (int i = t; i < 4096; i += 256) {
    int f = i >> 6, j = i & 63;
    qwt[i] = q_w[j*64 + f] * sl[f];
  }
  for (int i = t; i < 2592; i += 256) {
    int tap = i / 96, oc = i % 96;
    w2t[i] = upc_w[oc*27 + tap];
  }
}

// ============================================================
// K4: per 64-token chunk: L = F.Cs^T, e = exp(L) (no max; |L| small since fea unit-norm
// per column), partial e^T.F and sum(e) per block.
// ============================================================
__global__ __launch_bounds__(256) void k4_assign(
    const float* __restrict__ Fb, const float* __restrict__ cs,
    float* __restrict__ ncpart, float* __restrict__ zpart)
{
  __shared__ float Fl[64][65], Csl[64][65], El[64][65];
  const int t = threadIdx.x, nb = blockIdx.x;
  for (int i = t; i < 4096; i += 256) {
    int n = i >> 6, f = i & 63;
    Fl[n][f] = Fb[nb*4096 + i];
    Csl[n][f] = cs[i];
  }
  __syncthreads();
  { // phase A: e = exp(F . Cs^T)
    const int n = t & 63, kq = t >> 6;
    float a[16];
    #pragma unroll
    for (int i = 0; i < 16; ++i) a[i] = 0.f;
    #pragma unroll 8
    for (int f = 0; f < 64; ++f) {
      const float fv = Fl[n][f];
      #pragma unroll
      for (int i = 0; i < 16; ++i) a[i] += fv * Csl[kq*16+i][f];
    }
    #pragma unroll
    for (int i = 0; i < 16; ++i) El[n][kq*16+i] = __expf(a[i]);
  }
  __syncthreads();
  { // phase B: partial NC[k][f] = sum_n e[n][k]*F[n][f], Z[k] = sum_n e[n][k]
    const int k0 = (t >> 4) * 4, f0 = (t & 15) * 4;
    float acc[4][4], za[4];
    #pragma unroll
    for (int i = 0; i < 4; ++i) {
      za[i] = 0.f;
      #pragma unroll
      for (int j = 0; j < 4; ++j) acc[i][j] = 0.f;
    }
    for (int n = 0; n < 64; ++n) {
      float ev[4], fv[4];
      #pragma unroll
      for (int i = 0; i < 4; ++i) ev[i] = El[n][k0+i];
      #pragma unroll
      for (int j = 0; j < 4; ++j) fv[j] = Fl[n][f0+j];
      #pragma unroll
      for (int i = 0; i < 4; ++i) {
        za[i] += ev[i];
        #pragma unroll
        for (int j = 0; j < 4; ++j) acc[i][j] += ev[i] * fv[j];
      }
    }
    #pragma unroll
    for (int i = 0; i < 4; ++i)
      #pragma unroll
      for (int j = 0; j < 4; ++j)
        ncpart[(long)nb*4096 + (k0+i)*64 + f0+j] = acc[i][j];
    if (f0 == 0) {
      #pragma unroll
      for (int i = 0; i < 4; ++i) zpart[nb*64 + k0+i] = za[i];
    }
  }
}

// ============================================================
// K5a: reduce partials -> NC[k][f] = (sum e*F)/Z[k] * Sinv[f]
// ============================================================
__global__ __launch_bounds__(256) void k5a_nc(
    const float* __restrict__ ncpart, const float* __restrict__ zpart,
    const float* __restrict__ sinv, float* __restrict__ ncout)
{
  __shared__ float Zl[64], Sl[64];
  const int t = threadIdx.x, b = blockIdx.x;
  if (t < 64) {
    float z = 0.f;
    for (int p = 0; p < 128; ++p) z += zpart[p*64 + t];
    Zl[t] = z; Sl[t] = sinv[t];
  }
  __syncthreads();
  const int idx = b*256 + t;
  float s = 0.f;
  for (int p = 0; p < 128; ++p) s += ncpart[(long)p*4096 + idx];
  const int k = idx >> 6, f = idx & 63;
  ncout[idx] = s / Zl[k] * Sl[f];
}

// ============================================================
// K5b: kv = NC @ kv_w^T + kv_b -> kT[j][k] (pre-scaled 1/8, transposed), v[k][j]
// ============================================================
__global__ __launch_bounds__(256) void k5b_kv(
    const float* __restrict__ nc, const float* __restrict__ kv_w,
    const float* __restrict__ kv_b, float* __restrict__ kt, float* __restrict__ vv)
{
  __shared__ float NCl[64][65];
  const int t = threadIdx.x, b = blockIdx.x;
  for (int i = t; i < 4096; i += 256) NCl[i>>6][i&63] = nc[i];
  __syncthreads();
  const int idx = b*256 + t;     // 0..8191
  const int half = idx >> 12, rr = idx & 4095;
  int k, row;
  if (half == 0) { row = rr >> 6; k = rr & 63; }          // kT[j][k]
  else           { k = rr >> 6;  row = 64 + (rr & 63); }  // v[k][jv]
  float a = kv_b[row];
  #pragma unroll
  for (int c = 0; c < 64; ++c) a += NCl[k][c] * kv_w[row*64 + c];
  if (half == 0) kt[row*64 + k] = a * 0.125f;
  else           vv[k*64 + (row-64)] = a;
}

// ============================================================
// K6: wave-per-token attention. lane = feature/cluster index.
// q = F*QWT + q_b ; a = q.kT ; softmax over 64 lanes ; o = attn.v ; scatter to o1 volume
// ============================================================
__global__ __launch_bounds__(256) void k6_attn(
    const float* __restrict__ Fb, const float* __restrict__ qwt_g,
    const float* __restrict__ kt_g, const float* __restrict__ vv_g,
    const float* __restrict__ q_b, float* __restrict__ o1)
{
  __shared__ float qwt[64][65], kt[64][65], vl[64][65];
  const int t = threadIdx.x, b = blockIdx.x;
  for (int i = t; i < 4096; i += 256) {
    int n = i >> 6, m = i & 63;
    qwt[n][m] = qwt_g[i]; kt[n][m] = kt_g[i]; vl[n][m] = vv_g[i];
  }
  __syncthreads();
  const int lane = t & 63, wid = t >> 6;
  const float qb = q_b[lane];
  for (int it = 0; it < 4; ++it) {
    const int n = b*16 + wid*4 + it;
    const float Fv = Fb[n*64 + lane];
    float q = qb;
    #pragma unroll
    for (int f = 0; f < 64; ++f) q += __shfl(Fv, f) * qwt[f][lane];
    float a = 0.f;
    #pragma unroll
    for (int j = 0; j < 64; ++j) a += __shfl(q, j) * kt[j][lane];
    const float e = __expf(a);
    float s = e;
    s += __shfl_xor(s, 1);  s += __shfl_xor(s, 2);  s += __shfl_xor(s, 4);
    s += __shfl_xor(s, 8);  s += __shfl_xor(s, 16); s += __shfl_xor(s, 32);
    const float attn = e / s;
    float o = 0.f;
    #pragma unroll
    for (int k = 0; k < 64; ++k) o += __shfl(attn, k) * vl[k][lane];
    const int bd = n >> 10, bh = (n >> 5) & 31, bw = n & 31;
    const int pd = lane >> 4, ph = (lane >> 2) & 3, pw = lane & 3;
    o1[((bd*4+pd)*HH + (bh*4+ph))*WW + (bw*4+pw)] = o;
  }
}

// ============================================================
// K7: upc conv (1->96ch) + residual; per-thread cached weight quad (27 x float4 regs),
// fully coalesced float4 x-read / out-write.
// ============================================================
__global__ __launch_bounds__(192) void k7_upc(
    const float* __restrict__ o1, const float* __restrict__ w2t,
    const float* __restrict__ upc_b, const float* __restrict__ x,
    float* __restrict__ out)
{
  __shared__ float ol[9][132];
  const int t = threadIdx.x, r = blockIdx.x;
  const int d = r >> 7, h = r & 127;
  for (int i = t; i < 9*132; i += 192) {
    const int q = i / 132, wp = i % 132;
    const int kd = q / 3, kh = q % 3;
    const int dd = d + kd - 1, h2 = h + kh - 1, w = wp - 1;
    float v = 0.f;
    if (dd >= 0 && dd < DD && h2 >= 0 && h2 < HH && wp >= 1 && wp <= 128)
      v = o1[((long)(dd*HH + h2))*WW + w];
    ol[q][wp] = v;
  }
  __syncthreads();
  const int oc4 = t % 24, wg = t / 24;   // 24 oc-quads x 8 w-groups
  float4 w2[27];
  #pragma unroll
  for (int tap = 0; tap < 27; ++tap)
    w2[tap] = *(const float4*)&w2t[tap*96 + oc4*4];
  const float4 bias = *(const float4*)&upc_b[oc4*4];
  for (int i = 0; i < 16; ++i) {
    const int w = wg*16 + i;
    float4 a = bias;
    #pragma unroll
    for (int kd = 0; kd < 3; ++kd)
      #pragma unroll
      for (int kh = 0; kh < 3; ++kh)
        #pragma unroll
        for (int kw = 0; kw < 3; ++kw) {
          const float ov = ol[kd*3+kh][w+kw];
          const float4 wv = w2[kd*9 + kh*3 + kw];
          a.x += ov*wv.x; a.y += ov*wv.y; a.z += ov*wv.z; a.w += ov*wv.w;
        }
    const long base = ((long)r*WW + w)*CCH + oc4*4;
    const float4 xv = *(const float4*)&x[base];
    a.x += xv.x; a.y += xv.y; a.z += xv.z; a.w += xv.w;
    *(float4*)&out[base] = a;
  }
}

// ============================================================
extern "C" void kernel_launch(void* const* d_in, const int* in_sizes, int n_in,
                              void* d_out, int out_size, void* d_ws, size_t ws_size,
                              hipStream_t stream) {
  const float* x     = (const float*)d_in[0];
  const float* cent  = (const float*)d_in[1];
  const float* dwc_w = (const float*)d_in[2];
  const float* dwc_b = (const float*)d_in[3];
  const float* upc_w = (const float*)d_in[4];
  const float* upc_b = (const float*)d_in[5];
  const float* q_w   = (const float*)d_in[6];
  const float* q_b   = (const float*)d_in[7];
  const float* kv_w  = (const float*)d_in[8];
  const float* kv_b  = (const float*)d_in[9];
  float* out = (float*)d_out;
  float* ws  = (float*)d_ws;

  if (ws_size < (size_t)WS_FLOATS * sizeof(float)) return;  // need ~25.3 MB scratch

  float* z1     = ws + Z1_OFF;
  float* Fb     = ws + F_OFF;
  float* ncpart = ws + NCP_OFF;
  float* zpart  = ws + ZP_OFF;
  float* ssum   = ws + SSUM_OFF;
  float* sinv   = ws + SINV_OFF;
  float* cs     = ws + CS_OFF;
  float* qwt    = ws + QWT_OFF;
  float* w2t    = ws + W2T_OFF;
  float* nc     = ws + NCC_OFF;
  float* kt     = ws + KT_OFF;
  float* vv     = ws + VV_OFF;
  float* o1     = ws + O1_OFF;

  hipMemsetAsync((void*)ssum, 0, 64*sizeof(float), stream);

  k1_zplanes<<<NROW, 128, 0, stream>>>(x, dwc_w, z1);
  k2_combine<<<NROW, 128, 0, stream>>>(z1, dwc_b, Fb, ssum);
  k3_prep  <<<1, 256, 0, stream>>>(ssum, cent, q_w, upc_w, sinv, cs, qwt, w2t);
  k4_assign<<<128, 256, 0, stream>>>(Fb, cs, ncpart, zpart);
  k5a_nc   <<<16, 256, 0, stream>>>(ncpart, zpart, sinv, nc);
  k5b_kv   <<<32, 256, 0, stream>>>(nc, kv_w, kv_b, kt, vv);
  k6_attn  <<<512, 256, 0, stream>>>(Fb, qwt, kt, vv, q_b, o1);
  k7_upc   <<<NROW, 192, 0, stream>>>(o1, w2t, upc_b, x, out);
}

// Round 2
// 642.189 us; speedup vs baseline: 1.0718x; 1.0718x over previous
//
#include <hip/hip_runtime.h>

#define DD 32
#define HH 128
#define WW 128
#define CCH 96
#define NROW (DD*HH)          // 4096
#define NVOX (NROW*WW)        // 524288
#define NTOK 8192
#define NCLU 64

// ---- workspace layout (float offsets) ----
#define Z1_OFF    0ll
#define F_OFF     (9ll*NVOX)                  // 4718592
#define NCP_OFF   (F_OFF + NVOX)              // 5242880  (128 x 4096)
#define ZP_OFF    (NCP_OFF + 128ll*4096)      // 5767168  (128 x 64)
#define SSUM_OFF  (ZP_OFF + 8192)             // 5775360  (64)
#define SINV_OFF  (SSUM_OFF + 64)             // 5775424  (64)
#define CS_OFF    (SINV_OFF + 64)             // 5775488  (4096)
#define QWT_OFF   (CS_OFF + 4096)             // 5779584  (4096)
#define W2T_OFF   (QWT_OFF + 4096)            // 5783680  (2592)
#define NCC_OFF   (W2T_OFF + 2592)            // 5786272  (4096)
#define KT_OFF    (NCC_OFF + 4096)            // 5790368  (4096)
#define VV_OFF    (KT_OFF + 4096)             // 5794464  (4096)
#define O1_OFF    (VV_OFF + 4096)             // 5798560  (524288)
#define WS_FLOATS (O1_OFF + NVOX)             // 6322848

// ============================================================
// K1 (rewritten): per-thread channel contraction, no x staging.
// thread (r, w): c27[tap] = sum_c x[r,w,c] * W[c,tap]   (2592 FMA, weights in SGPRs)
// then fold w-taps through a small LDS exchange:
//   z'[j=(kd,kh)][r,w] = sum_kw c27_{w+kw-1}[j*3+kw]   (halo = zero-pad)
// block = 256 threads = 2 rows; LDS 29.7 KB -> ~20 waves/CU.
// ============================================================
__global__ __launch_bounds__(256) void k1_zplanes(
    const float* __restrict__ x, const float* __restrict__ wg,
    float* __restrict__ z1)
{
  __shared__ float csm[2][128][29];   // stride 29 (odd) -> conflict-free
  const int t = threadIdx.x;
  const int half = t >> 7, w = t & 127;
  const int r = blockIdx.x * 2 + half;        // d*128 + h
  const float* xp = &x[((long)r * WW + w) * CCH];

  float c27[27];
  #pragma unroll
  for (int i = 0; i < 27; ++i) c27[i] = 0.f;

  for (int c0 = 0; c0 < CCH; c0 += 8) {
    const float4 va = *(const float4*)(xp + c0);
    const float4 vb = *(const float4*)(xp + c0 + 4);
    const float xv[8] = {va.x, va.y, va.z, va.w, vb.x, vb.y, vb.z, vb.w};
    #pragma unroll
    for (int cc = 0; cc < 8; ++cc) {
      const float* wrow = &wg[(c0 + cc) * 27];   // uniform index -> s_load
      const float xc = xv[cc];
      #pragma unroll
      for (int tap = 0; tap < 27; ++tap)
        c27[tap] += xc * wrow[tap];
    }
  }

  #pragma unroll
  for (int tap = 0; tap < 27; ++tap) csm[half][w][tap] = c27[tap];
  __syncthreads();

  float zz[9];
  #pragma unroll
  for (int j = 0; j < 9; ++j) {
    float s = 0.f;
    #pragma unroll
    for (int kw = 0; kw < 3; ++kw) {
      const int ws = w + kw - 1;
      if (ws >= 0 && ws < 128) s += csm[half][ws][j*3 + kw];
    }
    zz[j] = s;
  }
  #pragma unroll
  for (int j = 0; j < 9; ++j)
    z1[(long)j * NVOX + (long)r * WW + w] = zz[j];
}

// ============================================================
// K2: gather 9 shifted planes -> dnx, write token-layout F, accumulate per-f sumsq
// ============================================================
__global__ __launch_bounds__(128) void k2_combine(
    const float* __restrict__ z1, const float* __restrict__ dwc_b,
    float* __restrict__ Fb, float* __restrict__ ssum)
{
  const int r = blockIdx.x;
  const int t = threadIdx.x;
  const int d = r >> 7, h = r & 127;
  float y = dwc_b[0];
  #pragma unroll
  for (int kd = 0; kd < 3; ++kd) {
    const int dd = d + kd - 1;
    if (dd < 0 || dd >= DD) continue;
    #pragma unroll
    for (int kh = 0; kh < 3; ++kh) {
      const int h2 = h + kh - 1;
      if (h2 < 0 || h2 >= HH) continue;
      y += z1[(long)(kd*3+kh)*NVOX + (long)(dd*HH + h2)*WW + t];
    }
  }
  const int n = (d>>2)*1024 + (h>>2)*32 + (t>>2);
  const int f = (d&3)*16 + (h&3)*4 + (t&3);
  Fb[n*64 + f] = y;
  float s = y*y;
  s += __shfl_xor(s, 4);  s += __shfl_xor(s, 8);
  s += __shfl_xor(s, 16); s += __shfl_xor(s, 32);
  if ((t & 63) < 4) atomicAdd(&ssum[(d&3)*16 + (h&3)*4 + (t&3)], s);
}

// ============================================================
// K3: Sinv = 1/max(sqrt(ssum),eps); fold into centroids (Cs) and q_w (QWT, transposed);
//     build transposed upc weights W2T[tap][oc].
// ============================================================
__global__ __launch_bounds__(256) void k3_prep(
    const float* __restrict__ ssum, const float* __restrict__ centroids,
    const float* __restrict__ q_w, const float* __restrict__ upc_w,
    float* __restrict__ sinv, float* __restrict__ cs,
    float* __restrict__ qwt, float* __restrict__ w2t)
{
  __shared__ float sl[64];
  const int t = threadIdx.x;
  if (t < 64) {
    float v = 1.f / fmaxf(sqrtf(ssum[t]), 1e-12f);
    sinv[t] = v; sl[t] = v;
  }
  __syncthreads();
  for (int i = t; i < 4096; i += 256) cs[i] = centroids[i] * sl[i & 63];
  for (int i = t; i < 4096; i += 256) {
    int f = i >> 6, j = i & 63;
    qwt[i] = q_w[j*64 + f] * sl[f];
  }
  for (int i = t; i < 2592; i += 256) {
    int tap = i / 96, oc = i % 96;
    w2t[i] = upc_w[oc*27 + tap];
  }
}

// ============================================================
// K4: per 64-token chunk: L = F.Cs^T, e = exp(L) (no max; |L| small since fea unit-norm
// per column), partial e^T.F and sum(e) per block.
// ============================================================
__global__ __launch_bounds__(256) void k4_assign(
    const float* __restrict__ Fb, const float* __restrict__ cs,
    float* __restrict__ ncpart, float* __restrict__ zpart)
{
  __shared__ float Fl[64][65], Csl[64][65], El[64][65];
  const int t = threadIdx.x, nb = blockIdx.x;
  for (int i = t; i < 4096; i += 256) {
    int n = i >> 6, f = i & 63;
    Fl[n][f] = Fb[nb*4096 + i];
    Csl[n][f] = cs[i];
  }
  __syncthreads();
  { // phase A: e = exp(F . Cs^T)
    const int n = t & 63, kq = t >> 6;
    float a[16];
    #pragma unroll
    for (int i = 0; i < 16; ++i) a[i] = 0.f;
    #pragma unroll 8
    for (int f = 0; f < 64; ++f) {
      const float fv = Fl[n][f];
      #pragma unroll
      for (int i = 0; i < 16; ++i) a[i] += fv * Csl[kq*16+i][f];
    }
    #pragma unroll
    for (int i = 0; i < 16; ++i) El[n][kq*16+i] = __expf(a[i]);
  }
  __syncthreads();
  { // phase B: partial NC[k][f] = sum_n e[n][k]*F[n][f], Z[k] = sum_n e[n][k]
    const int k0 = (t >> 4) * 4, f0 = (t & 15) * 4;
    float acc[4][4], za[4];
    #pragma unroll
    for (int i = 0; i < 4; ++i) {
      za[i] = 0.f;
      #pragma unroll
      for (int j = 0; j < 4; ++j) acc[i][j] = 0.f;
    }
    for (int n = 0; n < 64; ++n) {
      float ev[4], fv[4];
      #pragma unroll
      for (int i = 0; i < 4; ++i) ev[i] = El[n][k0+i];
      #pragma unroll
      for (int j = 0; j < 4; ++j) fv[j] = Fl[n][f0+j];
      #pragma unroll
      for (int i = 0; i < 4; ++i) {
        za[i] += ev[i];
        #pragma unroll
        for (int j = 0; j < 4; ++j) acc[i][j] += ev[i] * fv[j];
      }
    }
    #pragma unroll
    for (int i = 0; i < 4; ++i)
      #pragma unroll
      for (int j = 0; j < 4; ++j)
        ncpart[(long)nb*4096 + (k0+i)*64 + f0+j] = acc[i][j];
    if (f0 == 0) {
      #pragma unroll
      for (int i = 0; i < 4; ++i) zpart[nb*64 + k0+i] = za[i];
    }
  }
}

// ============================================================
// K5a: reduce partials -> NC[k][f] = (sum e*F)/Z[k] * Sinv[f]
// ============================================================
__global__ __launch_bounds__(256) void k5a_nc(
    const float* __restrict__ ncpart, const float* __restrict__ zpart,
    const float* __restrict__ sinv, float* __restrict__ ncout)
{
  __shared__ float Zl[64], Sl[64];
  const int t = threadIdx.x, b = blockIdx.x;
  if (t < 64) {
    float z = 0.f;
    for (int p = 0; p < 128; ++p) z += zpart[p*64 + t];
    Zl[t] = z; Sl[t] = sinv[t];
  }
  __syncthreads();
  const int idx = b*256 + t;
  float s = 0.f;
  for (int p = 0; p < 128; ++p) s += ncpart[(long)p*4096 + idx];
  const int k = idx >> 6, f = idx & 63;
  ncout[idx] = s / Zl[k] * Sl[f];
}

// ============================================================
// K5b: kv = NC @ kv_w^T + kv_b -> kT[j][k] (pre-scaled 1/8, transposed), v[k][j]
// ============================================================
__global__ __launch_bounds__(256) void k5b_kv(
    const float* __restrict__ nc, const float* __restrict__ kv_w,
    const float* __restrict__ kv_b, float* __restrict__ kt, float* __restrict__ vv)
{
  __shared__ float NCl[64][65];
  const int t = threadIdx.x, b = blockIdx.x;
  for (int i = t; i < 4096; i += 256) NCl[i>>6][i&63] = nc[i];
  __syncthreads();
  const int idx = b*256 + t;     // 0..8191
  const int half = idx >> 12, rr = idx & 4095;
  int k, row;
  if (half == 0) { row = rr >> 6; k = rr & 63; }          // kT[j][k]
  else           { k = rr >> 6;  row = 64 + (rr & 63); }  // v[k][jv]
  float a = kv_b[row];
  #pragma unroll
  for (int c = 0; c < 64; ++c) a += NCl[k][c] * kv_w[row*64 + c];
  if (half == 0) kt[row*64 + k] = a * 0.125f;
  else           vv[k*64 + (row-64)] = a;
}

// ============================================================
// K6: wave-per-token attention. lane = feature/cluster index.
// q = F*QWT + q_b ; a = q.kT ; softmax over 64 lanes ; o = attn.v ; scatter to o1 volume
// ============================================================
__global__ __launch_bounds__(256) void k6_attn(
    const float* __restrict__ Fb, const float* __restrict__ qwt_g,
    const float* __restrict__ kt_g, const float* __restrict__ vv_g,
    const float* __restrict__ q_b, float* __restrict__ o1)
{
  __shared__ float qwt[64][65], kt[64][65], vl[64][65];
  const int t = threadIdx.x, b = blockIdx.x;
  for (int i = t; i < 4096; i += 256) {
    int n = i >> 6, m = i & 63;
    qwt[n][m] = qwt_g[i]; kt[n][m] = kt_g[i]; vl[n][m] = vv_g[i];
  }
  __syncthreads();
  const int lane = t & 63, wid = t >> 6;
  const float qb = q_b[lane];
  for (int it = 0; it < 4; ++it) {
    const int n = b*16 + wid*4 + it;
    const float Fv = Fb[n*64 + lane];
    float q = qb;
    #pragma unroll
    for (int f = 0; f < 64; ++f) q += __shfl(Fv, f) * qwt[f][lane];
    float a = 0.f;
    #pragma unroll
    for (int j = 0; j < 64; ++j) a += __shfl(q, j) * kt[j][lane];
    const float e = __expf(a);
    float s = e;
    s += __shfl_xor(s, 1);  s += __shfl_xor(s, 2);  s += __shfl_xor(s, 4);
    s += __shfl_xor(s, 8);  s += __shfl_xor(s, 16); s += __shfl_xor(s, 32);
    const float attn = e / s;
    float o = 0.f;
    #pragma unroll
    for (int k = 0; k < 64; ++k) o += __shfl(attn, k) * vl[k][lane];
    const int bd = n >> 10, bh = (n >> 5) & 31, bw = n & 31;
    const int pd = lane >> 4, ph = (lane >> 2) & 3, pw = lane & 3;
    o1[((bd*4+pd)*HH + (bh*4+ph))*WW + (bw*4+pw)] = o;
  }
}

// ============================================================
// K7: upc conv (1->96ch) + residual; per-thread cached weight quad (27 x float4 regs),
// fully coalesced float4 x-read / out-write.
// ============================================================
__global__ __launch_bounds__(192) void k7_upc(
    const float* __restrict__ o1, const float* __restrict__ w2t,
    const float* __restrict__ upc_b, const float* __restrict__ x,
    float* __restrict__ out)
{
  __shared__ float ol[9][132];
  const int t = threadIdx.x, r = blockIdx.x;
  const int d = r >> 7, h = r & 127;
  for (int i = t; i < 9*132; i += 192) {
    const int q = i / 132, wp = i % 132;
    const int kd = q / 3, kh = q % 3;
    const int dd = d + kd - 1, h2 = h + kh - 1, w = wp - 1;
    float v = 0.f;
    if (dd >= 0 && dd < DD && h2 >= 0 && h2 < HH && wp >= 1 && wp <= 128)
      v = o1[((long)(dd*HH + h2))*WW + w];
    ol[q][wp] = v;
  }
  __syncthreads();
  const int oc4 = t % 24, wg = t / 24;   // 24 oc-quads x 8 w-groups
  float4 w2[27];
  #pragma unroll
  for (int tap = 0; tap < 27; ++tap)
    w2[tap] = *(const float4*)&w2t[tap*96 + oc4*4];
  const float4 bias = *(const float4*)&upc_b[oc4*4];
  for (int i = 0; i < 16; ++i) {
    const int w = wg*16 + i;
    float4 a = bias;
    #pragma unroll
    for (int kd = 0; kd < 3; ++kd)
      #pragma unroll
      for (int kh = 0; kh < 3; ++kh)
        #pragma unroll
        for (int kw = 0; kw < 3; ++kw) {
          const float ov = ol[kd*3+kh][w+kw];
          const float4 wv = w2[kd*9 + kh*3 + kw];
          a.x += ov*wv.x; a.y += ov*wv.y; a.z += ov*wv.z; a.w += ov*wv.w;
        }
    const long base = ((long)r*WW + w)*CCH + oc4*4;
    const float4 xv = *(const float4*)&x[base];
    a.x += xv.x; a.y += xv.y; a.z += xv.z; a.w += xv.w;
    *(float4*)&out[base] = a;
  }
}

// ============================================================
extern "C" void kernel_launch(void* const* d_in, const int* in_sizes, int n_in,
                              void* d_out, int out_size, void* d_ws, size_t ws_size,
                              hipStream_t stream) {
  const float* x     = (const float*)d_in[0];
  const float* cent  = (const float*)d_in[1];
  const float* dwc_w = (const float*)d_in[2];
  const float* dwc_b = (const float*)d_in[3];
  const float* upc_w = (const float*)d_in[4];
  const float* upc_b = (const float*)d_in[5];
  const float* q_w   = (const float*)d_in[6];
  const float* q_b   = (const float*)d_in[7];
  const float* kv_w  = (const float*)d_in[8];
  const float* kv_b  = (const float*)d_in[9];
  float* out = (float*)d_out;
  float* ws  = (float*)d_ws;

  if (ws_size < (size_t)WS_FLOATS * sizeof(float)) return;  // need ~25.3 MB scratch

  float* z1     = ws + Z1_OFF;
  float* Fb     = ws + F_OFF;
  float* ncpart = ws + NCP_OFF;
  float* zpart  = ws + ZP_OFF;
  float* ssum   = ws + SSUM_OFF;
  float* sinv   = ws + SINV_OFF;
  float* cs     = ws + CS_OFF;
  float* qwt    = ws + QWT_OFF;
  float* w2t    = ws + W2T_OFF;
  float* nc     = ws + NCC_OFF;
  float* kt     = ws + KT_OFF;
  float* vv     = ws + VV_OFF;
  float* o1     = ws + O1_OFF;

  hipMemsetAsync((void*)ssum, 0, 64*sizeof(float), stream);

  k1_zplanes<<<NROW/2, 256, 0, stream>>>(x, dwc_w, z1);
  k2_combine<<<NROW, 128, 0, stream>>>(z1, dwc_b, Fb, ssum);
  k3_prep  <<<1, 256, 0, stream>>>(ssum, cent, q_w, upc_w, sinv, cs, qwt, w2t);
  k4_assign<<<128, 256, 0, stream>>>(Fb, cs, ncpart, zpart);
  k5a_nc   <<<16, 256, 0, stream>>>(ncpart, zpart, sinv, nc);
  k5b_kv   <<<32, 256, 0, stream>>>(nc, kv_w, kv_b, kt, vv);
  k6_attn  <<<512, 256, 0, stream>>>(Fb, qwt, kt, vv, q_b, o1);
  k7_upc   <<<NROW, 192, 0, stream>>>(o1, w2t, upc_b, x, out);
}

// Round 3
// 621.792 us; speedup vs baseline: 1.1070x; 1.0328x over previous
//
#include <hip/hip_runtime.h>

#define DD 32
#define HH 128
#define WW 128
#define CCH 96
#define NROW (DD*HH)          // 4096
#define NVOX (NROW*WW)        // 524288
#define NTOK 8192
#define NCLU 64

// ---- workspace layout (float offsets) ----
#define Z1_OFF    0ll
#define F_OFF     (9ll*NVOX)                  // 4718592
#define NCP_OFF   (F_OFF + NVOX)              // 5242880  (128 x 4096)
#define ZP_OFF    (NCP_OFF + 128ll*4096)      // 5767168  (128 x 64)
#define SSUM_OFF  (ZP_OFF + 8192)             // 5775360  (64)
#define SINV_OFF  (SSUM_OFF + 64)             // 5775424  (64)
#define CS_OFF    (SINV_OFF + 64)             // 5775488  (4096)
#define QWT_OFF   (CS_OFF + 4096)             // 5779584  (4096)
#define W2T_OFF   (QWT_OFF + 4096)            // 5783680  (2592)
#define NCC_OFF   (W2T_OFF + 2592)            // 5786272  (4096)
#define KT_OFF    (NCC_OFF + 4096)            // 5790368  (4096)
#define VV_OFF    (KT_OFF + 4096)             // 5794464  (4096)
#define O1_OFF    (VV_OFF + 4096)             // 5798560  (524288)
#define WS_FLOATS (O1_OFF + NVOX)             // 6322848

// ============================================================
// K1: per-thread channel contraction, no x staging.
// ============================================================
__global__ __launch_bounds__(256) void k1_zplanes(
    const float* __restrict__ x, const float* __restrict__ wg,
    float* __restrict__ z1)
{
  __shared__ float csm[2][128][29];   // stride 29 (odd) -> conflict-free
  const int t = threadIdx.x;
  const int half = t >> 7, w = t & 127;
  const int r = blockIdx.x * 2 + half;        // d*128 + h
  const float* xp = &x[((long)r * WW + w) * CCH];

  float c27[27];
  #pragma unroll
  for (int i = 0; i < 27; ++i) c27[i] = 0.f;

  for (int c0 = 0; c0 < CCH; c0 += 8) {
    const float4 va = *(const float4*)(xp + c0);
    const float4 vb = *(const float4*)(xp + c0 + 4);
    const float xv[8] = {va.x, va.y, va.z, va.w, vb.x, vb.y, vb.z, vb.w};
    #pragma unroll
    for (int cc = 0; cc < 8; ++cc) {
      const float* wrow = &wg[(c0 + cc) * 27];   // uniform index -> s_load
      const float xc = xv[cc];
      #pragma unroll
      for (int tap = 0; tap < 27; ++tap)
        c27[tap] += xc * wrow[tap];
    }
  }

  #pragma unroll
  for (int tap = 0; tap < 27; ++tap) csm[half][w][tap] = c27[tap];
  __syncthreads();

  float zz[9];
  #pragma unroll
  for (int j = 0; j < 9; ++j) {
    float s = 0.f;
    #pragma unroll
    for (int kw = 0; kw < 3; ++kw) {
      const int ws = w + kw - 1;
      if (ws >= 0 && ws < 128) s += csm[half][ws][j*3 + kw];
    }
    zz[j] = s;
  }
  #pragma unroll
  for (int j = 0; j < 9; ++j)
    z1[(long)j * NVOX + (long)r * WW + w] = zz[j];
}

// ============================================================
// K2: gather 9 shifted planes -> dnx, write token-layout F, accumulate per-f sumsq
// ============================================================
__global__ __launch_bounds__(128) void k2_combine(
    const float* __restrict__ z1, const float* __restrict__ dwc_b,
    float* __restrict__ Fb, float* __restrict__ ssum)
{
  const int r = blockIdx.x;
  const int t = threadIdx.x;
  const int d = r >> 7, h = r & 127;
  float y = dwc_b[0];
  #pragma unroll
  for (int kd = 0; kd < 3; ++kd) {
    const int dd = d + kd - 1;
    if (dd < 0 || dd >= DD) continue;
    #pragma unroll
    for (int kh = 0; kh < 3; ++kh) {
      const int h2 = h + kh - 1;
      if (h2 < 0 || h2 >= HH) continue;
      y += z1[(long)(kd*3+kh)*NVOX + (long)(dd*HH + h2)*WW + t];
    }
  }
  const int n = (d>>2)*1024 + (h>>2)*32 + (t>>2);
  const int f = (d&3)*16 + (h&3)*4 + (t&3);
  Fb[n*64 + f] = y;
  float s = y*y;
  s += __shfl_xor(s, 4);  s += __shfl_xor(s, 8);
  s += __shfl_xor(s, 16); s += __shfl_xor(s, 32);
  if ((t & 63) < 4) atomicAdd(&ssum[(d&3)*16 + (h&3)*4 + (t&3)], s);
}

// ============================================================
// K3: Sinv = 1/max(sqrt(ssum),eps); fold into centroids (Cs) and q_w (QWT, transposed);
//     build transposed upc weights W2T[tap][oc].
// ============================================================
__global__ __launch_bounds__(256) void k3_prep(
    const float* __restrict__ ssum, const float* __restrict__ centroids,
    const float* __restrict__ q_w, const float* __restrict__ upc_w,
    float* __restrict__ sinv, float* __restrict__ cs,
    float* __restrict__ qwt, float* __restrict__ w2t)
{
  __shared__ float sl[64];
  const int t = threadIdx.x;
  if (t < 64) {
    float v = 1.f / fmaxf(sqrtf(ssum[t]), 1e-12f);
    sinv[t] = v; sl[t] = v;
  }
  __syncthreads();
  for (int i = t; i < 4096; i += 256) cs[i] = centroids[i] * sl[i & 63];
  for (int i = t; i < 4096; i += 256) {
    int f = i >> 6, j = i & 63;
    qwt[i] = q_w[j*64 + f] * sl[f];
  }
  for (int i = t; i < 2592; i += 256) {
    int tap = i / 96, oc = i % 96;
    w2t[i] = upc_w[oc*27 + tap];
  }
}

// ============================================================
// K4: per 64-token chunk: L = F.Cs^T, e = exp(L), partial e^T.F and sum(e) per block.
// ============================================================
__global__ __launch_bounds__(256) void k4_assign(
    const float* __restrict__ Fb, const float* __restrict__ cs,
    float* __restrict__ ncpart, float* __restrict__ zpart)
{
  __shared__ float Fl[64][65], Csl[64][65], El[64][65];
  const int t = threadIdx.x, nb = blockIdx.x;
  for (int i = t; i < 4096; i += 256) {
    int n = i >> 6, f = i & 63;
    Fl[n][f] = Fb[nb*4096 + i];
    Csl[n][f] = cs[i];
  }
  __syncthreads();
  { // phase A: e = exp(F . Cs^T)
    const int n = t & 63, kq = t >> 6;
    float a[16];
    #pragma unroll
    for (int i = 0; i < 16; ++i) a[i] = 0.f;
    #pragma unroll 8
    for (int f = 0; f < 64; ++f) {
      const float fv = Fl[n][f];
      #pragma unroll
      for (int i = 0; i < 16; ++i) a[i] += fv * Csl[kq*16+i][f];
    }
    #pragma unroll
    for (int i = 0; i < 16; ++i) El[n][kq*16+i] = __expf(a[i]);
  }
  __syncthreads();
  { // phase B: partial NC[k][f] = sum_n e[n][k]*F[n][f], Z[k] = sum_n e[n][k]
    const int k0 = (t >> 4) * 4, f0 = (t & 15) * 4;
    float acc[4][4], za[4];
    #pragma unroll
    for (int i = 0; i < 4; ++i) {
      za[i] = 0.f;
      #pragma unroll
      for (int j = 0; j < 4; ++j) acc[i][j] = 0.f;
    }
    for (int n = 0; n < 64; ++n) {
      float ev[4], fv[4];
      #pragma unroll
      for (int i = 0; i < 4; ++i) ev[i] = El[n][k0+i];
      #pragma unroll
      for (int j = 0; j < 4; ++j) fv[j] = Fl[n][f0+j];
      #pragma unroll
      for (int i = 0; i < 4; ++i) {
        za[i] += ev[i];
        #pragma unroll
        for (int j = 0; j < 4; ++j) acc[i][j] += ev[i] * fv[j];
      }
    }
    #pragma unroll
    for (int i = 0; i < 4; ++i)
      #pragma unroll
      for (int j = 0; j < 4; ++j)
        ncpart[(long)nb*4096 + (k0+i)*64 + f0+j] = acc[i][j];
    if (f0 == 0) {
      #pragma unroll
      for (int i = 0; i < 4; ++i) zpart[nb*64 + k0+i] = za[i];
    }
  }
}

// ============================================================
// K5a: reduce partials -> NC[k][f] = (sum e*F)/Z[k] * Sinv[f]
// ============================================================
__global__ __launch_bounds__(256) void k5a_nc(
    const float* __restrict__ ncpart, const float* __restrict__ zpart,
    const float* __restrict__ sinv, float* __restrict__ ncout)
{
  __shared__ float Zl[64], Sl[64];
  const int t = threadIdx.x, b = blockIdx.x;
  if (t < 64) {
    float z = 0.f;
    for (int p = 0; p < 128; ++p) z += zpart[p*64 + t];
    Zl[t] = z; Sl[t] = sinv[t];
  }
  __syncthreads();
  const int idx = b*256 + t;
  float s = 0.f;
  for (int p = 0; p < 128; ++p) s += ncpart[(long)p*4096 + idx];
  const int k = idx >> 6, f = idx & 63;
  ncout[idx] = s / Zl[k] * Sl[f];
}

// ============================================================
// K5b: kv = NC @ kv_w^T + kv_b -> kT[j][k] (pre-scaled 1/8, transposed), v[k][j]
// ============================================================
__global__ __launch_bounds__(256) void k5b_kv(
    const float* __restrict__ nc, const float* __restrict__ kv_w,
    const float* __restrict__ kv_b, float* __restrict__ kt, float* __restrict__ vv)
{
  __shared__ float NCl[64][65];
  const int t = threadIdx.x, b = blockIdx.x;
  for (int i = t; i < 4096; i += 256) NCl[i>>6][i&63] = nc[i];
  __syncthreads();
  const int idx = b*256 + t;     // 0..8191
  const int half = idx >> 12, rr = idx & 4095;
  int k, row;
  if (half == 0) { row = rr >> 6; k = rr & 63; }          // kT[j][k]
  else           { k = rr >> 6;  row = 64 + (rr & 63); }  // v[k][jv]
  float a = kv_b[row];
  #pragma unroll
  for (int c = 0; c < 64; ++c) a += NCl[k][c] * kv_w[row*64 + c];
  if (half == 0) kt[row*64 + k] = a * 0.125f;
  else           vv[k*64 + (row-64)] = a;
}

// ============================================================
// K6: wave-per-token attention.
// ============================================================
__global__ __launch_bounds__(256) void k6_attn(
    const float* __restrict__ Fb, const float* __restrict__ qwt_g,
    const float* __restrict__ kt_g, const float* __restrict__ vv_g,
    const float* __restrict__ q_b, float* __restrict__ o1)
{
  __shared__ float qwt[64][65], kt[64][65], vl[64][65];
  const int t = threadIdx.x, b = blockIdx.x;
  for (int i = t; i < 4096; i += 256) {
    int n = i >> 6, m = i & 63;
    qwt[n][m] = qwt_g[i]; kt[n][m] = kt_g[i]; vl[n][m] = vv_g[i];
  }
  __syncthreads();
  const int lane = t & 63, wid = t >> 6;
  const float qb = q_b[lane];
  for (int it = 0; it < 4; ++it) {
    const int n = b*16 + wid*4 + it;
    const float Fv = Fb[n*64 + lane];
    float q = qb;
    #pragma unroll
    for (int f = 0; f < 64; ++f) q += __shfl(Fv, f) * qwt[f][lane];
    float a = 0.f;
    #pragma unroll
    for (int j = 0; j < 64; ++j) a += __shfl(q, j) * kt[j][lane];
    const float e = __expf(a);
    float s = e;
    s += __shfl_xor(s, 1);  s += __shfl_xor(s, 2);  s += __shfl_xor(s, 4);
    s += __shfl_xor(s, 8);  s += __shfl_xor(s, 16); s += __shfl_xor(s, 32);
    const float attn = e / s;
    float o = 0.f;
    #pragma unroll
    for (int k = 0; k < 64; ++k) o += __shfl(attn, k) * vl[k][lane];
    const int bd = n >> 10, bh = (n >> 5) & 31, bw = n & 31;
    const int pd = lane >> 4, ph = (lane >> 2) & 3, pw = lane & 3;
    o1[((bd*4+pd)*HH + (bh*4+ph))*WW + (bw*4+pw)] = o;
  }
}

// ============================================================
// K7 (rewritten): upc conv (1->96ch) + residual.
// block 384 = 24 oc-quads x 16 w-groups of 8; plane-by-plane register-shift
// reuse: per plane q, each thread loads ol[q][w0..w0+9] ONCE (2x ds_read_b128
// + 2x b32), reuses across the 3 kw taps; weights 3 float4/plane from L1.
// Cuts LDS instrs ~12x and VGPR to ~64 -> high occupancy.
// ============================================================
__global__ __launch_bounds__(384) void k7_upc(
    const float* __restrict__ o1, const float* __restrict__ w2t,
    const float* __restrict__ upc_b, const float* __restrict__ x,
    float* __restrict__ out)
{
  __shared__ float ol[9][132];
  const int t = threadIdx.x, r = blockIdx.x;
  const int d = r >> 7, h = r & 127;
  for (int i = t; i < 9*132; i += 384) {
    const int q = i / 132, wp = i % 132;
    const int kd = q / 3, kh = q % 3;
    const int dd = d + kd - 1, h2 = h + kh - 1, w = wp - 1;
    float v = 0.f;
    if (dd >= 0 && dd < DD && h2 >= 0 && h2 < HH && wp >= 1 && wp <= 128)
      v = o1[((long)(dd*HH + h2))*WW + w];
    ol[q][wp] = v;
  }
  __syncthreads();

  const int oc4 = t % 24, wg = t / 24;   // 24 oc-quads x 16 w-groups
  const int w0 = wg * 8;                 // outputs w0..w0+7; stencil wp = w0..w0+9
  const float4 bias = *(const float4*)&upc_b[oc4*4];
  float4 acc[8];
  #pragma unroll
  for (int i = 0; i < 8; ++i) acc[i] = bias;

  #pragma unroll
  for (int q = 0; q < 9; ++q) {
    // load 10 stencil values for this plane (16B-aligned: w0 % 8 == 0)
    float row[10];
    {
      const float4 ra = *(const float4*)&ol[q][w0];
      const float4 rb = *(const float4*)&ol[q][w0+4];
      row[0]=ra.x; row[1]=ra.y; row[2]=ra.z; row[3]=ra.w;
      row[4]=rb.x; row[5]=rb.y; row[6]=rb.z; row[7]=rb.w;
      row[8]=ol[q][w0+8]; row[9]=ol[q][w0+9];
    }
    #pragma unroll
    for (int kw = 0; kw < 3; ++kw) {
      const float4 wv = *(const float4*)&w2t[(q*3+kw)*96 + oc4*4];
      #pragma unroll
      for (int i = 0; i < 8; ++i) {
        const float ov = row[i+kw];
        acc[i].x += ov*wv.x; acc[i].y += ov*wv.y;
        acc[i].z += ov*wv.z; acc[i].w += ov*wv.w;
      }
    }
  }

  #pragma unroll
  for (int i = 0; i < 8; ++i) {
    const int w = w0 + i;
    const long base = ((long)r*WW + w)*CCH + oc4*4;
    const float4 xv = *(const float4*)&x[base];
    float4 a = acc[i];
    a.x += xv.x; a.y += xv.y; a.z += xv.z; a.w += xv.w;
    *(float4*)&out[base] = a;
  }
}

// ============================================================
extern "C" void kernel_launch(void* const* d_in, const int* in_sizes, int n_in,
                              void* d_out, int out_size, void* d_ws, size_t ws_size,
                              hipStream_t stream) {
  const float* x     = (const float*)d_in[0];
  const float* cent  = (const float*)d_in[1];
  const float* dwc_w = (const float*)d_in[2];
  const float* dwc_b = (const float*)d_in[3];
  const float* upc_w = (const float*)d_in[4];
  const float* upc_b = (const float*)d_in[5];
  const float* q_w   = (const float*)d_in[6];
  const float* q_b   = (const float*)d_in[7];
  const float* kv_w  = (const float*)d_in[8];
  const float* kv_b  = (const float*)d_in[9];
  float* out = (float*)d_out;
  float* ws  = (float*)d_ws;

  if (ws_size < (size_t)WS_FLOATS * sizeof(float)) return;  // need ~25.3 MB scratch

  float* z1     = ws + Z1_OFF;
  float* Fb     = ws + F_OFF;
  float* ncpart = ws + NCP_OFF;
  float* zpart  = ws + ZP_OFF;
  float* ssum   = ws + SSUM_OFF;
  float* sinv   = ws + SINV_OFF;
  float* cs     = ws + CS_OFF;
  float* qwt    = ws + QWT_OFF;
  float* w2t    = ws + W2T_OFF;
  float* nc     = ws + NCC_OFF;
  float* kt     = ws + KT_OFF;
  float* vv     = ws + VV_OFF;
  float* o1     = ws + O1_OFF;

  hipMemsetAsync((void*)ssum, 0, 64*sizeof(float), stream);

  k1_zplanes<<<NROW/2, 256, 0, stream>>>(x, dwc_w, z1);
  k2_combine<<<NROW, 128, 0, stream>>>(z1, dwc_b, Fb, ssum);
  k3_prep  <<<1, 256, 0, stream>>>(ssum, cent, q_w, upc_w, sinv, cs, qwt, w2t);
  k4_assign<<<128, 256, 0, stream>>>(Fb, cs, ncpart, zpart);
  k5a_nc   <<<16, 256, 0, stream>>>(ncpart, zpart, sinv, nc);
  k5b_kv   <<<32, 256, 0, stream>>>(nc, kv_w, kv_b, kt, vv);
  k6_attn  <<<512, 256, 0, stream>>>(Fb, qwt, kt, vv, q_b, o1);
  k7_upc   <<<NROW, 384, 0, stream>>>(o1, w2t, upc_b, x, out);
}

// Round 4
// 609.049 us; speedup vs baseline: 1.1301x; 1.0209x over previous
//
#include <hip/hip_runtime.h>

#define DD 32
#define HH 128
#define WW 128
#define CCH 96
#define NROW (DD*HH)          // 4096
#define NVOX (NROW*WW)        // 524288
#define NTOK 8192
#define NCLU 64

// ---- workspace layout (float offsets) ----
#define Z1_OFF    0ll
#define F_OFF     (9ll*NVOX)                  // 4718592
#define NCP_OFF   (F_OFF + NVOX)              // 5242880  (128 x 4096)
#define ZP_OFF    (NCP_OFF + 128ll*4096)      // 5767168  (128 x 64)
#define SSUM_OFF  (ZP_OFF + 8192)             // 5775360  (64)
#define SINV_OFF  (SSUM_OFF + 64)             // 5775424  (64)
#define CS_OFF    (SINV_OFF + 64)             // 5775488  (4096)
#define QWT_OFF   (CS_OFF + 4096)             // 5779584  (4096)
#define W2T_OFF   (QWT_OFF + 4096)            // 5783680  (2592)
#define NCC_OFF   (W2T_OFF + 2592)            // 5786272  (4096)
#define KT_OFF    (NCC_OFF + 4096)            // 5790368  (4096)
#define VV_OFF    (KT_OFF + 4096)             // 5794464  (4096)
#define O1_OFF    (VV_OFF + 4096)             // 5798560  (524288)
#define WS_FLOATS (O1_OFF + NVOX)             // 6322848

// ============================================================
// K1: per-thread channel contraction. Load ALL 96 channels (24 x float4,
// full 64B lines) up-front -> zero serialized stalls, then 2592 FMAs with
// SGPR weights. Small LDS exchange folds the w-taps into 9 z-planes.
// ============================================================
__global__ __launch_bounds__(256) void k1_zplanes(
    const float* __restrict__ x, const float* __restrict__ wg,
    float* __restrict__ z1)
{
  __shared__ float csm[2][128][29];   // stride 29 (odd) -> conflict-free
  const int t = threadIdx.x;
  const int half = t >> 7, w = t & 127;
  const int r = blockIdx.x * 2 + half;        // d*128 + h
  const float* xp = &x[((long)r * WW + w) * CCH];

  // issue all 24 float4 loads up-front (MLP; lines fully consumed)
  float xv[96];
  #pragma unroll
  for (int q = 0; q < 24; ++q)
    *(float4*)&xv[q*4] = *(const float4*)(xp + q*4);

  float c27[27];
  #pragma unroll
  for (int i = 0; i < 27; ++i) c27[i] = 0.f;

  #pragma unroll
  for (int cc = 0; cc < 96; ++cc) {
    const float* wrow = &wg[cc*27];   // uniform -> s_load, SGPR operand in FMA
    const float xc = xv[cc];
    #pragma unroll
    for (int tap = 0; tap < 27; ++tap)
      c27[tap] += xc * wrow[tap];
  }

  #pragma unroll
  for (int tap = 0; tap < 27; ++tap) csm[half][w][tap] = c27[tap];
  __syncthreads();

  float zz[9];
  #pragma unroll
  for (int j = 0; j < 9; ++j) {
    float s = 0.f;
    #pragma unroll
    for (int kw = 0; kw < 3; ++kw) {
      const int ws = w + kw - 1;
      if (ws >= 0 && ws < 128) s += csm[half][ws][j*3 + kw];
    }
    zz[j] = s;
  }
  #pragma unroll
  for (int j = 0; j < 9; ++j)
    z1[(long)j * NVOX + (long)r * WW + w] = zz[j];
}

// ============================================================
// K2: gather 9 shifted planes -> dnx, write token-layout F, accumulate per-f sumsq
// ============================================================
__global__ __launch_bounds__(128) void k2_combine(
    const float* __restrict__ z1, const float* __restrict__ dwc_b,
    float* __restrict__ Fb, float* __restrict__ ssum)
{
  const int r = blockIdx.x;
  const int t = threadIdx.x;
  const int d = r >> 7, h = r & 127;
  float y = dwc_b[0];
  #pragma unroll
  for (int kd = 0; kd < 3; ++kd) {
    const int dd = d + kd - 1;
    if (dd < 0 || dd >= DD) continue;
    #pragma unroll
    for (int kh = 0; kh < 3; ++kh) {
      const int h2 = h + kh - 1;
      if (h2 < 0 || h2 >= HH) continue;
      y += z1[(long)(kd*3+kh)*NVOX + (long)(dd*HH + h2)*WW + t];
    }
  }
  const int n = (d>>2)*1024 + (h>>2)*32 + (t>>2);
  const int f = (d&3)*16 + (h&3)*4 + (t&3);
  Fb[n*64 + f] = y;
  float s = y*y;
  s += __shfl_xor(s, 4);  s += __shfl_xor(s, 8);
  s += __shfl_xor(s, 16); s += __shfl_xor(s, 32);
  if ((t & 63) < 4) atomicAdd(&ssum[(d&3)*16 + (h&3)*4 + (t&3)], s);
}

// ============================================================
// K3: Sinv = 1/max(sqrt(ssum),eps); fold into centroids (Cs) and q_w (QWT, transposed);
//     build transposed upc weights W2T[tap][oc].
// ============================================================
__global__ __launch_bounds__(256) void k3_prep(
    const float* __restrict__ ssum, const float* __restrict__ centroids,
    const float* __restrict__ q_w, const float* __restrict__ upc_w,
    float* __restrict__ sinv, float* __restrict__ cs,
    float* __restrict__ qwt, float* __restrict__ w2t)
{
  __shared__ float sl[64];
  const int t = threadIdx.x;
  if (t < 64) {
    float v = 1.f / fmaxf(sqrtf(ssum[t]), 1e-12f);
    sinv[t] = v; sl[t] = v;
  }
  __syncthreads();
  for (int i = t; i < 4096; i += 256) cs[i] = centroids[i] * sl[i & 63];
  for (int i = t; i < 4096; i += 256) {
    int f = i >> 6, j = i & 63;
    qwt[i] = q_w[j*64 + f] * sl[f];
  }
  for (int i = t; i < 2592; i += 256) {
    int tap = i / 96, oc = i % 96;
    w2t[i] = upc_w[oc*27 + tap];
  }
}

// ============================================================
// K4: 512 blocks: block b -> chunk nb = b>>2 (64 tokens), k-quarter K0 = (b&3)*16.
// phase A: e = exp(F . Cs^T) for 16 clusters; phase B: partial e^T.F and sum(e).
// Same ncpart/zpart layout as before (disjoint writes), k5a unchanged.
// ============================================================
__global__ __launch_bounds__(256) void k4_assign(
    const float* __restrict__ Fb, const float* __restrict__ cs,
    float* __restrict__ ncpart, float* __restrict__ zpart)
{
  __shared__ float Fl[64][65], Csl[16][65], El[64][17];
  const int t = threadIdx.x;
  const int nb = blockIdx.x >> 2, K0 = (blockIdx.x & 3) * 16;
  for (int i = t; i < 4096; i += 256) Fl[i>>6][i&63] = Fb[nb*4096 + i];
  for (int i = t; i < 1024; i += 256) Csl[i>>6][i&63] = cs[(K0 + (i>>6))*64 + (i&63)];
  __syncthreads();
  { // phase A: n = t&63 token row, kk = (t>>6)*4 cluster quad
    const int n = t & 63, kk = (t >> 6) * 4;
    float a[4] = {0.f, 0.f, 0.f, 0.f};
    #pragma unroll 8
    for (int f = 0; f < 64; ++f) {
      const float fv = Fl[n][f];
      #pragma unroll
      for (int i = 0; i < 4; ++i) a[i] += fv * Csl[kk+i][f];
    }
    #pragma unroll
    for (int i = 0; i < 4; ++i) El[n][kk+i] = __expf(a[i]);
  }
  __syncthreads();
  { // phase B: f = t&63, cluster quad kq = (t>>6)*4
    const int f = t & 63, kq = (t >> 6) * 4;
    float acc[4] = {0.f,0.f,0.f,0.f}, za[4] = {0.f,0.f,0.f,0.f};
    for (int n = 0; n < 64; ++n) {
      const float fv = Fl[n][f];
      #pragma unroll
      for (int i = 0; i < 4; ++i) {
        const float ev = El[n][kq+i];   // wave-uniform -> broadcast
        acc[i] += ev * fv;
        za[i]  += ev;
      }
    }
    #pragma unroll
    for (int i = 0; i < 4; ++i)
      ncpart[(long)nb*4096 + (K0+kq+i)*64 + f] = acc[i];
    if (f == 0) {
      #pragma unroll
      for (int i = 0; i < 4; ++i) zpart[nb*64 + K0+kq+i] = za[i];
    }
  }
}

// ============================================================
// K5a: reduce partials -> NC[k][f] = (sum e*F)/Z[k] * Sinv[f]
// ============================================================
__global__ __launch_bounds__(256) void k5a_nc(
    const float* __restrict__ ncpart, const float* __restrict__ zpart,
    const float* __restrict__ sinv, float* __restrict__ ncout)
{
  __shared__ float Zl[64], Sl[64];
  const int t = threadIdx.x, b = blockIdx.x;
  if (t < 64) {
    float z = 0.f;
    for (int p = 0; p < 128; ++p) z += zpart[p*64 + t];
    Zl[t] = z; Sl[t] = sinv[t];
  }
  __syncthreads();
  const int idx = b*256 + t;
  float s = 0.f;
  for (int p = 0; p < 128; ++p) s += ncpart[(long)p*4096 + idx];
  const int k = idx >> 6, f = idx & 63;
  ncout[idx] = s / Zl[k] * Sl[f];
}

// ============================================================
// K5b: kv = NC @ kv_w^T + kv_b -> kT[j][k] (pre-scaled 1/8, transposed), v[k][j]
// ============================================================
__global__ __launch_bounds__(256) void k5b_kv(
    const float* __restrict__ nc, const float* __restrict__ kv_w,
    const float* __restrict__ kv_b, float* __restrict__ kt, float* __restrict__ vv)
{
  __shared__ float NCl[64][65];
  const int t = threadIdx.x, b = blockIdx.x;
  for (int i = t; i < 4096; i += 256) NCl[i>>6][i&63] = nc[i];
  __syncthreads();
  const int idx = b*256 + t;     // 0..8191
  const int half = idx >> 12, rr = idx & 4095;
  int k, row;
  if (half == 0) { row = rr >> 6; k = rr & 63; }          // kT[j][k]
  else           { k = rr >> 6;  row = 64 + (rr & 63); }  // v[k][jv]
  float a = kv_b[row];
  #pragma unroll
  for (int c = 0; c < 64; ++c) a += NCl[k][c] * kv_w[row*64 + c];
  if (half == 0) kt[row*64 + k] = a * 0.125f;
  else           vv[k*64 + (row-64)] = a;
}

// ============================================================
// K6: wave-per-token attention.
// ============================================================
__global__ __launch_bounds__(256) void k6_attn(
    const float* __restrict__ Fb, const float* __restrict__ qwt_g,
    const float* __restrict__ kt_g, const float* __restrict__ vv_g,
    const float* __restrict__ q_b, float* __restrict__ o1)
{
  __shared__ float qwt[64][65], kt[64][65], vl[64][65];
  const int t = threadIdx.x, b = blockIdx.x;
  for (int i = t; i < 4096; i += 256) {
    int n = i >> 6, m = i & 63;
    qwt[n][m] = qwt_g[i]; kt[n][m] = kt_g[i]; vl[n][m] = vv_g[i];
  }
  __syncthreads();
  const int lane = t & 63, wid = t >> 6;
  const float qb = q_b[lane];
  for (int it = 0; it < 4; ++it) {
    const int n = b*16 + wid*4 + it;
    const float Fv = Fb[n*64 + lane];
    float q = qb;
    #pragma unroll
    for (int f = 0; f < 64; ++f) q += __shfl(Fv, f) * qwt[f][lane];
    float a = 0.f;
    #pragma unroll
    for (int j = 0; j < 64; ++j) a += __shfl(q, j) * kt[j][lane];
    const float e = __expf(a);
    float s = e;
    s += __shfl_xor(s, 1);  s += __shfl_xor(s, 2);  s += __shfl_xor(s, 4);
    s += __shfl_xor(s, 8);  s += __shfl_xor(s, 16); s += __shfl_xor(s, 32);
    const float attn = e / s;
    float o = 0.f;
    #pragma unroll
    for (int k = 0; k < 64; ++k) o += __shfl(attn, k) * vl[k][lane];
    const int bd = n >> 10, bh = (n >> 5) & 31, bw = n & 31;
    const int pd = lane >> 4, ph = (lane >> 2) & 3, pw = lane & 3;
    o1[((bd*4+pd)*HH + (bh*4+ph))*WW + (bw*4+pw)] = o;
  }
}

// ============================================================
// K7: upc conv (1->96ch) + residual. x loads issued FIRST (held in VGPRs
// through staging+compute -> one latency exposure); plane-by-plane stencil
// with register-shift reuse.
// ============================================================
__global__ __launch_bounds__(384) void k7_upc(
    const float* __restrict__ o1, const float* __restrict__ w2t,
    const float* __restrict__ upc_b, const float* __restrict__ x,
    float* __restrict__ out)
{
  __shared__ float ol[9][132];
  const int t = threadIdx.x, r = blockIdx.x;
  const int d = r >> 7, h = r & 127;

  const int oc4 = t % 24, wg = t / 24;   // 24 oc-quads x 16 w-groups
  const int w0 = wg * 8;                 // outputs w0..w0+7
  const long base0 = ((long)r*WW + w0)*CCH + oc4*4;

  // 1) issue residual x loads up-front; consumed only in the epilogue
  float4 xv[8];
  #pragma unroll
  for (int i = 0; i < 8; ++i)
    xv[i] = *(const float4*)&x[base0 + (long)i*CCH];

  // 2) stage o1 stencil rows
  for (int i = t; i < 9*132; i += 384) {
    const int q = i / 132, wp = i % 132;
    const int kd = q / 3, kh = q % 3;
    const int dd = d + kd - 1, h2 = h + kh - 1, w = wp - 1;
    float v = 0.f;
    if (dd >= 0 && dd < DD && h2 >= 0 && h2 < HH && wp >= 1 && wp <= 128)
      v = o1[((long)(dd*HH + h2))*WW + w];
    ol[q][wp] = v;
  }
  __syncthreads();

  const float4 bias = *(const float4*)&upc_b[oc4*4];
  float4 acc[8];
  #pragma unroll
  for (int i = 0; i < 8; ++i) acc[i] = bias;

  #pragma unroll
  for (int q = 0; q < 9; ++q) {
    float row[10];
    {
      const float4 ra = *(const float4*)&ol[q][w0];
      const float4 rb = *(const float4*)&ol[q][w0+4];
      row[0]=ra.x; row[1]=ra.y; row[2]=ra.z; row[3]=ra.w;
      row[4]=rb.x; row[5]=rb.y; row[6]=rb.z; row[7]=rb.w;
      row[8]=ol[q][w0+8]; row[9]=ol[q][w0+9];
    }
    #pragma unroll
    for (int kw = 0; kw < 3; ++kw) {
      const float4 wv = *(const float4*)&w2t[(q*3+kw)*96 + oc4*4];
      #pragma unroll
      for (int i = 0; i < 8; ++i) {
        const float ov = row[i+kw];
        acc[i].x += ov*wv.x; acc[i].y += ov*wv.y;
        acc[i].z += ov*wv.z; acc[i].w += ov*wv.w;
      }
    }
  }

  #pragma unroll
  for (int i = 0; i < 8; ++i) {
    float4 a = acc[i];
    a.x += xv[i].x; a.y += xv[i].y; a.z += xv[i].z; a.w += xv[i].w;
    *(float4*)&out[base0 + (long)i*CCH] = a;
  }
}

// ============================================================
extern "C" void kernel_launch(void* const* d_in, const int* in_sizes, int n_in,
                              void* d_out, int out_size, void* d_ws, size_t ws_size,
                              hipStream_t stream) {
  const float* x     = (const float*)d_in[0];
  const float* cent  = (const float*)d_in[1];
  const float* dwc_w = (const float*)d_in[2];
  const float* dwc_b = (const float*)d_in[3];
  const float* upc_w = (const float*)d_in[4];
  const float* upc_b = (const float*)d_in[5];
  const float* q_w   = (const float*)d_in[6];
  const float* q_b   = (const float*)d_in[7];
  const float* kv_w  = (const float*)d_in[8];
  const float* kv_b  = (const float*)d_in[9];
  float* out = (float*)d_out;
  float* ws  = (float*)d_ws;

  if (ws_size < (size_t)WS_FLOATS * sizeof(float)) return;  // need ~25.3 MB scratch

  float* z1     = ws + Z1_OFF;
  float* Fb     = ws + F_OFF;
  float* ncpart = ws + NCP_OFF;
  float* zpart  = ws + ZP_OFF;
  float* ssum   = ws + SSUM_OFF;
  float* sinv   = ws + SINV_OFF;
  float* cs     = ws + CS_OFF;
  float* qwt    = ws + QWT_OFF;
  float* w2t    = ws + W2T_OFF;
  float* nc     = ws + NCC_OFF;
  float* kt     = ws + KT_OFF;
  float* vv     = ws + VV_OFF;
  float* o1     = ws + O1_OFF;

  hipMemsetAsync((void*)ssum, 0, 64*sizeof(float), stream);

  k1_zplanes<<<NROW/2, 256, 0, stream>>>(x, dwc_w, z1);
  k2_combine<<<NROW, 128, 0, stream>>>(z1, dwc_b, Fb, ssum);
  k3_prep  <<<1, 256, 0, stream>>>(ssum, cent, q_w, upc_w, sinv, cs, qwt, w2t);
  k4_assign<<<512, 256, 0, stream>>>(Fb, cs, ncpart, zpart);
  k5a_nc   <<<16, 256, 0, stream>>>(ncpart, zpart, sinv, nc);
  k5b_kv   <<<32, 256, 0, stream>>>(nc, kv_w, kv_b, kt, vv);
  k6_attn  <<<512, 256, 0, stream>>>(Fb, qwt, kt, vv, q_b, o1);
  k7_upc   <<<NROW, 384, 0, stream>>>(o1, w2t, upc_b, x, out);
}